// Round 6
// baseline (68.064 us; speedup 1.0000x reference)
//
#include <hip/hip_runtime.h>
#include <hip/hip_bf16.h>
#include <math.h>

// Problem dims (fixed by reference)
#define B_ 16
#define T_ 1024
#define C_ 768
#define H_ 64

typedef __attribute__((ext_vector_type(8))) short bf16x8;
typedef __attribute__((ext_vector_type(4))) short bf16x4;
typedef __attribute__((ext_vector_type(4))) float f32x4;

// fp32 -> bf16 (round-to-nearest-even)
__device__ __forceinline__ short f2bf(float f) {
  union { float f; unsigned u; } un;
  un.f = f;
  unsigned r = un.u + 0x7FFFu + ((un.u >> 16) & 1u);
  return (short)(r >> 16);
}

// ---------------------------------------------------------------------------
// Kernel 1: W prep in MFMA fragment order.
// frag_id = ks*12 + ct  (ks = k-step of 32, ct = global col-tile 0..11,
// mat = ct>>2). Element: wfrag[frag_id*512 + l*8 + j] = W_mat[k][col], with
// col = (ct&3)*16 + (l&15), k = ks*32 + (l>>4)*8 + j.
// ---------------------------------------------------------------------------
__global__ __launch_bounds__(256) void prep_w(
    const float* __restrict__ Wq, const float* __restrict__ Wk,
    const float* __restrict__ Wv, short* __restrict__ wfrag) {
  const int o = blockIdx.x * 256 + threadIdx.x;   // 0..147455
  const int j = o & 7;
  const int l = (o >> 3) & 63;
  const int fid = o >> 9;
  const int ct = fid % 12;
  const int ks = fid / 12;
  const int mat = ct >> 2;
  const int col = (ct & 3) * 16 + (l & 15);
  const int k = ks * 32 + (l >> 4) * 8 + j;
  const float* W = (mat == 0) ? Wq : (mat == 1) ? Wk : Wv;
  wfrag[o] = f2bf(W[(size_t)k * H_ + col]);
}

// ---------------------------------------------------------------------------
// Kernel 2: QKV projection + fused V-transpose. Block = 256 thr = 4 waves,
// one 16-row tile; wave w owns K-quarter w (192 k = 3 chunks of 64).
// x staged per-wave via global_load_lds (pre-swizzled source, XOR-swizzled
// ds_read), double-buffered, no barriers in main loop. 4 partials merged in
// LDS; epilogue writes qk[row][128] (q|k) AND vt[b][n][t] (V transposed).
// ---------------------------------------------------------------------------
#define QKV_LDSF 12544  // floats: staging 4w*2*1024=8192; pool 4*16*196=12544

__global__ __launch_bounds__(256, 3) void qkv_gemm(
    const float* __restrict__ x, const short* __restrict__ wfrag,
    const float* __restrict__ bq, const float* __restrict__ bk,
    const float* __restrict__ bv,
    short* __restrict__ qk, short* __restrict__ vt) {
  __shared__ float lds[QKV_LDSF];
  const int rt = blockIdx.x;            // 16-row tile (global over B*T rows)
  const int tid = threadIdx.x;
  const int w  = tid >> 6;              // wave = K-quarter
  const int l  = tid & 63;
  const int lo = l & 15, hi = l >> 4;

  float* stg = lds + w * 2048;          // 2 bufs x 1024 floats (4KB each)
  const char* xb = (const char*)(x + (size_t)rt * 16 * C_ + w * 192);

  // stage chunk c (64 k-floats x 16 rows = 4KB): 4 global_load_lds.
  auto STAGE = [&](int buf, int c) {
    #pragma unroll
    for (int s = 0; s < 4; ++s) {
      const int r = s * 4 + hi;
      const char* src = xb + (size_t)r * (C_ * 4) + (size_t)c * 256
                        + ((lo * 16) ^ ((r & 7) << 4));
      float* dst = stg + buf * 1024 + s * 256;  // wave-uniform base
      __builtin_amdgcn_global_load_lds(
          (const __attribute__((address_space(1))) void*)src,
          (__attribute__((address_space(3))) void*)dst, 16, 0, 0);
    }
  };

  f32x4 acc[12];
  #pragma unroll
  for (int ct = 0; ct < 12; ++ct) acc[ct] = (f32x4){0.f, 0.f, 0.f, 0.f};

  STAGE(0, 0);

  #pragma unroll
  for (int c = 0; c < 3; ++c) {
    const int buf = c & 1;
    __builtin_amdgcn_sched_barrier(0);
    // ---- W-frag loads for this chunk (24 coalesced 16B/lane, stay in flight)
    bf16x8 wfA[12], wfB[12];
    const int ksb = w * 6 + c * 2;
    #pragma unroll
    for (int ct = 0; ct < 12; ++ct) {
      wfA[ct] = *(const bf16x8*)(wfrag + ((size_t)(ksb * 12 + ct) << 9) + l * 8);
      wfB[ct] = *(const bf16x8*)(wfrag + ((size_t)((ksb + 1) * 12 + ct) << 9) + l * 8);
    }
    __builtin_amdgcn_sched_barrier(0);
    // ---- stage next chunk
    if (c < 2) STAGE(buf ^ 1, c + 1);
    __builtin_amdgcn_sched_barrier(0);
    // ---- wait for THIS chunk's stage only (W + next stage stay in flight)
    if (c < 2) { asm volatile("s_waitcnt vmcnt(28)" ::: "memory"); }
    else       { asm volatile("s_waitcnt vmcnt(24)" ::: "memory"); }
    __builtin_amdgcn_sched_barrier(0);
    // ---- A-frags from LDS (XOR-swz) + cvt + 24 MFMAs
    bf16x8 af0, af1;
    {
      const char* rp = (const char*)(stg + buf * 1024) + lo * 256;
      const int sw = (lo & 7) << 4;
      f32x4 x0 = *(const f32x4*)(rp + ((hi * 32)       ^ sw));
      f32x4 x1 = *(const f32x4*)(rp + ((hi * 32 + 16)  ^ sw));
      f32x4 x2 = *(const f32x4*)(rp + ((128 + hi * 32)      ^ sw));
      f32x4 x3 = *(const f32x4*)(rp + ((128 + hi * 32 + 16) ^ sw));
      #pragma unroll
      for (int j = 0; j < 4; ++j) {
        af0[j] = f2bf(x0[j]); af0[4 + j] = f2bf(x1[j]);
        af1[j] = f2bf(x2[j]); af1[4 + j] = f2bf(x3[j]);
      }
    }
    __builtin_amdgcn_s_setprio(1);
    #pragma unroll
    for (int ct = 0; ct < 12; ++ct)
      acc[ct] = __builtin_amdgcn_mfma_f32_16x16x32_bf16(af0, wfA[ct], acc[ct], 0, 0, 0);
    #pragma unroll
    for (int ct = 0; ct < 12; ++ct)
      acc[ct] = __builtin_amdgcn_mfma_f32_16x16x32_bf16(af1, wfB[ct], acc[ct], 0, 0, 0);
    __builtin_amdgcn_s_setprio(0);
  }

  // ---- merge 4 K-quarter partials through LDS (pool overlaps dead staging)
  __syncthreads();
  #pragma unroll
  for (int ct = 0; ct < 12; ++ct)
    #pragma unroll
    for (int r = 0; r < 4; ++r)
      lds[w * 3136 + (hi * 4 + r) * 196 + ct * 16 + lo] = acc[ct][r];
  __syncthreads();

  // ---- qk merge: thread -> row=tid>>4, cols c0..c0+7 in [0,128)
  {
    const int row = tid >> 4;
    const int c0 = (tid & 15) * 8;
    bf16x8 o;
    #pragma unroll
    for (int j = 0; j < 8; ++j) {
      const int col = c0 + j;
      float s = lds[row * 196 + col] + lds[3136 + row * 196 + col]
              + lds[6272 + row * 196 + col] + lds[9408 + row * 196 + col];
      s += (col < 64) ? bq[col] : bk[col - 64];
      o[j] = f2bf(s);
    }
    *(bf16x8*)(qk + ((size_t)(rt * 16 + row)) * 128 + c0) = o;
  }
  // ---- fused V-transpose: thread -> n=tid>>2, rows rq*4..rq*4+3
  {
    const int n = tid >> 2;
    const int rq = tid & 3;
    const int b = rt >> 6;
    const int tloc = (rt & 63) * 16;
    const float bias_v = bv[n];
    bf16x4 o;
    #pragma unroll
    for (int j = 0; j < 4; ++j) {
      const int row = rq * 4 + j;
      float s = lds[row * 196 + 128 + n] + lds[3136 + row * 196 + 128 + n]
              + lds[6272 + row * 196 + 128 + n] + lds[9408 + row * 196 + 128 + n];
      o[j] = f2bf(s + bias_v);
    }
    *(bf16x4*)(vt + ((size_t)(b * H_ + n)) * T_ + tloc + rq * 4) = o;
  }
}

// ---------------------------------------------------------------------------
// Kernel 3: flash attention, 4-way KV-split, swapped QK^T (structure
// unchanged from round 5; qk buffer stride 128, k at +64).
// ---------------------------------------------------------------------------
#define SCALE_LOG2E 0.18033688011114382f  // 0.125 * log2(e)

__global__ __launch_bounds__(256) void flash(
    const short* __restrict__ qk, const short* __restrict__ vt,
    float* __restrict__ out) {
  __shared__ __align__(16) short p_lds[4][16][72];
  __shared__ float o_sh[4][16][64];
  __shared__ float ml_sh[4][2][16];

  const int qt = (int)gridDim.x - 1 - (int)blockIdx.x;
  const int b = blockIdx.y;
  const int w = threadIdx.x >> 6;
  const int l = threadIdx.x & 63;
  const int lo = l & 15, hi = l >> 4;

  const int dtile = qt >> 2;
  const int ntot = dtile + 1;
  const int span = (ntot + 3) >> 2;
  const int kv0 = w * span;
  const int kv1 = min(ntot, kv0 + span);
  const int qr = qt & 3;

  const short* qrow = qk + (size_t)(b * T_ + qt * 16 + lo) * 128;  // q at +0
  bf16x8 qf0 = *(const bf16x8*)(qrow + hi * 8);
  bf16x8 qf1 = *(const bf16x8*)(qrow + 32 + hi * 8);

  float m_l = -1e30f;   // running max for q-row `lo` (log2 units)
  float l_l = 0.f;      // running denom for q-row `lo`
  f32x4 oacc[4];
  #pragma unroll
  for (int dt = 0; dt < 4; ++dt) oacc[dt] = (f32x4){0.f, 0.f, 0.f, 0.f};

  for (int kvt = kv0; kvt < kv1; ++kvt) {
    const bool diag = (kvt == dtile);
    const int nct = diag ? (qr + 1) : 4;

    // S^T tile: sv[ct][r] = S[key = ct*16 + hi*4 + r][q-row = lo]
    f32x4 sv[4];
    #pragma unroll
    for (int ct = 0; ct < 4; ++ct) sv[ct] = (f32x4){0.f, 0.f, 0.f, 0.f};
    __builtin_amdgcn_s_setprio(1);
    #pragma unroll
    for (int ct = 0; ct < 4; ++ct) {
      if (ct < nct) {
        const short* krow = qk + (size_t)(b * T_ + kvt * 64 + ct * 16 + lo) * 128 + 64;
        bf16x8 kf0 = *(const bf16x8*)(krow + hi * 8);
        bf16x8 kf1 = *(const bf16x8*)(krow + 32 + hi * 8);
        sv[ct] = __builtin_amdgcn_mfma_f32_16x16x32_bf16(kf0, qf0, sv[ct], 0, 0, 0);
        sv[ct] = __builtin_amdgcn_mfma_f32_16x16x32_bf16(kf1, qf1, sv[ct], 0, 0, 0);
      }
    }
    __builtin_amdgcn_s_setprio(0);

    // scale (log2 units) + causal mask
    #pragma unroll
    for (int ct = 0; ct < 4; ++ct) {
      #pragma unroll
      for (int r = 0; r < 4; ++r) {
        float s = (ct < nct) ? sv[ct][r] * SCALE_LOG2E : -1e30f;
        if (diag && ct == qr && (hi * 4 + r) > lo) s = -1e30f;
        sv[ct][r] = s;
      }
    }

    // online softmax for row `lo` (16 keys local; partners via xor 16/32)
    float tmax = sv[0][0];
    #pragma unroll
    for (int ct = 0; ct < 4; ++ct)
      #pragma unroll
      for (int r = 0; r < 4; ++r) tmax = fmaxf(tmax, sv[ct][r]);
    tmax = fmaxf(tmax, __shfl_xor(tmax, 16));
    tmax = fmaxf(tmax, __shfl_xor(tmax, 32));
    const float mn = fmaxf(m_l, tmax);
    const float corr = exp2f(m_l - mn);
    m_l = mn;
    float psum = 0.f;
    #pragma unroll
    for (int ct = 0; ct < 4; ++ct) {
      #pragma unroll
      for (int r = 0; r < 4; ++r) {
        float p = exp2f(sv[ct][r] - mn);
        sv[ct][r] = p;
        psum += p;
      }
    }
    psum += __shfl_xor(psum, 16);
    psum += __shfl_xor(psum, 32);
    l_l = l_l * corr + psum;

    // P -> bf16 (cvt_pk pairs), packed 8B write
    #pragma unroll
    for (int ct = 0; ct < 4; ++ct) {
      __hip_bfloat162 p01 = __float22bfloat162_rn(float2{sv[ct][0], sv[ct][1]});
      __hip_bfloat162 p23 = __float22bfloat162_rn(float2{sv[ct][2], sv[ct][3]});
      uint2 pk;
      pk.x = *reinterpret_cast<unsigned*>(&p01);
      pk.y = *reinterpret_cast<unsigned*>(&p23);
      *reinterpret_cast<uint2*>(&p_lds[w][lo][ct * 16 + hi * 4]) = pk;
    }

    // rescale oacc (rows hi*4+r): fetch corr of that row from lane lo==row
    #pragma unroll
    for (int r = 0; r < 4; ++r) {
      const float cr = __shfl(corr, hi * 4 + r);
      #pragma unroll
      for (int dt = 0; dt < 4; ++dt) oacc[dt][r] *= cr;
    }

    // O += P V
    bf16x8 pa0 = *(const bf16x8*)(&p_lds[w][lo][hi * 8]);
    bf16x8 pa1 = *(const bf16x8*)(&p_lds[w][lo][32 + hi * 8]);
    __builtin_amdgcn_s_setprio(1);
    #pragma unroll
    for (int dt = 0; dt < 4; ++dt) {
      const short* vrow = vt + (size_t)(b * H_ + dt * 16 + lo) * T_ + kvt * 64;
      bf16x8 vf0 = *(const bf16x8*)(vrow + hi * 8);
      bf16x8 vf1 = *(const bf16x8*)(vrow + 32 + hi * 8);
      oacc[dt] = __builtin_amdgcn_mfma_f32_16x16x32_bf16(pa0, vf0, oacc[dt], 0, 0, 0);
      oacc[dt] = __builtin_amdgcn_mfma_f32_16x16x32_bf16(pa1, vf1, oacc[dt], 0, 0, 0);
    }
    __builtin_amdgcn_s_setprio(0);
  }

  // publish partials
  #pragma unroll
  for (int dt = 0; dt < 4; ++dt)
    #pragma unroll
    for (int r = 0; r < 4; ++r)
      o_sh[w][hi * 4 + r][dt * 16 + lo] = oacc[dt][r];
  if (hi == 0) {
    ml_sh[w][0][lo] = m_l;
    ml_sh[w][1][lo] = l_l;
  }
  __syncthreads();

  // merge (log2 units)
  {
    const int row = threadIdx.x >> 4;
    const int c0 = (threadIdx.x & 15) * 4;
    float M = fmaxf(fmaxf(ml_sh[0][0][row], ml_sh[1][0][row]),
                    fmaxf(ml_sh[2][0][row], ml_sh[3][0][row]));
    float e[4];
    float L = 0.f;
    #pragma unroll
    for (int w2 = 0; w2 < 4; ++w2) {
      e[w2] = exp2f(ml_sh[w2][0][row] - M);
      L += ml_sh[w2][1][row] * e[w2];
    }
    f32x4 o;
    #pragma unroll
    for (int j = 0; j < 4; ++j) {
      float O = 0.f;
      #pragma unroll
      for (int w2 = 0; w2 < 4; ++w2) O += e[w2] * o_sh[w2][row][c0 + j];
      o[j] = O / L;
    }
    *(f32x4*)(out + (size_t)(b * T_ + qt * 16 + row) * H_ + c0) = o;
  }
}

// ---------------------------------------------------------------------------
extern "C" void kernel_launch(void* const* d_in, const int* in_sizes, int n_in,
                              void* d_out, int out_size, void* d_ws, size_t ws_size,
                              hipStream_t stream) {
  const float* x  = (const float*)d_in[0];
  const float* Wq = (const float*)d_in[1];
  const float* bq = (const float*)d_in[2];
  const float* Wk = (const float*)d_in[3];
  const float* bk = (const float*)d_in[4];
  const float* Wv = (const float*)d_in[5];
  const float* bv = (const float*)d_in[6];
  float* out = (float*)d_out;

  // workspace layout (shorts): wfrag | qk (stride 128) | vt
  short* wfrag = (short*)d_ws;
  short* qk = wfrag + (size_t)3 * H_ * C_;           // 147456
  short* vtb = qk + (size_t)B_ * T_ * 128;           // +2097152

  prep_w<<<dim3(576), dim3(256), 0, stream>>>(Wq, Wk, Wv, wfrag);
  qkv_gemm<<<dim3(1024), dim3(256), 0, stream>>>(x, wfrag, bq, bk, bv, qk, vtb);
  flash<<<dim3(T_ / 16, B_), dim3(256), 0, stream>>>(qk, vtb, out);
}

// Round 7
// 55.090 us; speedup vs baseline: 1.2355x; 1.2355x over previous
//
#include <hip/hip_runtime.h>
#include <hip/hip_bf16.h>
#include <math.h>

// Problem dims (fixed by reference)
#define B_ 16
#define T_ 1024
#define C_ 768
#define H_ 64

typedef __attribute__((ext_vector_type(8))) short bf16x8;
typedef __attribute__((ext_vector_type(4))) float f32x4;

// fp32 -> bf16 (round-to-nearest-even)
__device__ __forceinline__ short f2bf(float f) {
  union { float f; unsigned u; } un;
  un.f = f;
  unsigned r = un.u + 0x7FFFu + ((un.u >> 16) & 1u);
  return (short)(r >> 16);
}

// ---------------------------------------------------------------------------
// Kernel 1: W prep in MFMA fragment order (unchanged).
// ---------------------------------------------------------------------------
__global__ __launch_bounds__(256) void prep_w(
    const float* __restrict__ Wq, const float* __restrict__ Wk,
    const float* __restrict__ Wv, short* __restrict__ wfrag) {
  const int o = blockIdx.x * 256 + threadIdx.x;   // 0..147455
  const int j = o & 7;
  const int l = (o >> 3) & 63;
  const int fid = o >> 9;
  const int ct = fid % 12;
  const int ks = fid / 12;
  const int mat = ct >> 2;
  const int col = (ct & 3) * 16 + (l & 15);
  const int k = ks * 32 + (l >> 4) * 8 + j;
  const float* W = (mat == 0) ? Wq : (mat == 1) ? Wk : Wv;
  wfrag[o] = f2bf(W[(size_t)k * H_ + col]);
}

// ---------------------------------------------------------------------------
// Kernel 2: QKV projection. Round-5 structure (2 waves = 2 K-halves per
// 16-row tile) with TRIPLE-buffered x staging (prefetch depth 2) so the
// ~900cy stage latency is covered by two chunks of compute.
// ---------------------------------------------------------------------------
#define QKV_LDSF 6400  // floats: staging 2w*3*1024=6144; pool 2*16*196=6272

__global__ __launch_bounds__(128, 2) void qkv_gemm(
    const float* __restrict__ x, const short* __restrict__ wfrag,
    const float* __restrict__ bq, const float* __restrict__ bk,
    const float* __restrict__ bv, short* __restrict__ qkv) {
  __shared__ float lds[QKV_LDSF];
  const int rt = blockIdx.x;            // 16-row tile
  const int w  = threadIdx.x >> 6;      // wave = K-half
  const int l  = threadIdx.x & 63;
  const int lo = l & 15, hi = l >> 4;
  const int kh = w;

  float* stg = lds + w * 3072;          // 3 bufs x 1024 floats (4KB each)
  const char* xb = (const char*)(x + (size_t)rt * 16 * C_ + kh * 384);

  auto STAGE = [&](int buf, int c) {
    #pragma unroll
    for (int s = 0; s < 4; ++s) {
      const int r = s * 4 + hi;
      const char* src = xb + (size_t)r * (C_ * 4) + (size_t)c * 256
                        + ((lo * 16) ^ ((r & 7) << 4));
      float* dst = stg + buf * 1024 + s * 256;  // wave-uniform base
      __builtin_amdgcn_global_load_lds(
          (const __attribute__((address_space(1))) void*)src,
          (__attribute__((address_space(3))) void*)dst, 16, 0, 0);
    }
  };

  f32x4 acc[12];
  #pragma unroll
  for (int ct = 0; ct < 12; ++ct) acc[ct] = (f32x4){0.f, 0.f, 0.f, 0.f};

  STAGE(0, 0);
  STAGE(1, 1);

  #pragma unroll
  for (int c = 0; c < 6; ++c) {
    const int buf = c % 3;
    __builtin_amdgcn_sched_barrier(0);
    // ---- W-frag loads for this chunk (24 coalesced 16B/lane)
    bf16x8 wf0[12], wf1[12];
    const int ksb = kh * 12 + c * 2;
    #pragma unroll
    for (int ct = 0; ct < 12; ++ct) {
      wf0[ct] = *(const bf16x8*)(wfrag + ((size_t)(ksb * 12 + ct) << 9) + l * 8);
      wf1[ct] = *(const bf16x8*)(wfrag + ((size_t)((ksb + 1) * 12 + ct) << 9) + l * 8);
    }
    __builtin_amdgcn_sched_barrier(0);
    // ---- stage chunk c+2 (depth-2 prefetch)
    if (c < 4) STAGE((c + 2) % 3, c + 2);
    __builtin_amdgcn_sched_barrier(0);
    // ---- wait for THIS chunk's stage only.
    // outstanding allowed: W(c)=24 + stage(c+1)=4 (if c<5) + stage(c+2)=4 (if c<4)
    if (c < 4)      { asm volatile("s_waitcnt vmcnt(32)" ::: "memory"); }
    else if (c < 5) { asm volatile("s_waitcnt vmcnt(28)" ::: "memory"); }
    else            { asm volatile("s_waitcnt vmcnt(24)" ::: "memory"); }
    __builtin_amdgcn_sched_barrier(0);
    // ---- A-frags from LDS (XOR-swz) + cvt + 24 MFMAs
    bf16x8 af0, af1;
    {
      const char* rp = (const char*)(stg + buf * 1024) + lo * 256;
      const int sw = (lo & 7) << 4;
      f32x4 x0 = *(const f32x4*)(rp + ((hi * 32)       ^ sw));
      f32x4 x1 = *(const f32x4*)(rp + ((hi * 32 + 16)  ^ sw));
      f32x4 x2 = *(const f32x4*)(rp + ((128 + hi * 32)      ^ sw));
      f32x4 x3 = *(const f32x4*)(rp + ((128 + hi * 32 + 16) ^ sw));
      #pragma unroll
      for (int j = 0; j < 4; ++j) {
        af0[j] = f2bf(x0[j]); af0[4 + j] = f2bf(x1[j]);
        af1[j] = f2bf(x2[j]); af1[4 + j] = f2bf(x3[j]);
      }
    }
    __builtin_amdgcn_s_setprio(1);
    #pragma unroll
    for (int ct = 0; ct < 12; ++ct)
      acc[ct] = __builtin_amdgcn_mfma_f32_16x16x32_bf16(af0, wf0[ct], acc[ct], 0, 0, 0);
    #pragma unroll
    for (int ct = 0; ct < 12; ++ct)
      acc[ct] = __builtin_amdgcn_mfma_f32_16x16x32_bf16(af1, wf1[ct], acc[ct], 0, 0, 0);
    __builtin_amdgcn_s_setprio(0);
  }

  // ---- merge K-halves through LDS (pool overlaps staging; barrier first)
  __syncthreads();
  #pragma unroll
  for (int ct = 0; ct < 12; ++ct)
    #pragma unroll
    for (int r = 0; r < 4; ++r)
      lds[w * 3136 + (hi * 4 + r) * 196 + ct * 16 + lo] = acc[ct][r];
  __syncthreads();

  {
    const int row = threadIdx.x >> 3;          // 0..15
    const int c0 = (threadIdx.x & 7) * 24;     // 0..168
    bf16x8 o0, o1, o2;
    #pragma unroll
    for (int j = 0; j < 24; ++j) {
      const int col = c0 + j;
      float s = lds[row * 196 + col] + lds[3136 + row * 196 + col];
      const int mat = col >> 6;
      const float* bb = (mat == 0) ? bq : (mat == 1) ? bk : bv;
      s += bb[col & 63];
      const short v = f2bf(s);
      if (j < 8) o0[j] = v; else if (j < 16) o1[j - 8] = v; else o2[j - 16] = v;
    }
    short* op = qkv + ((size_t)(rt * 16 + row)) * 192 + c0;
    *(bf16x8*)(op)      = o0;
    *(bf16x8*)(op + 8)  = o1;
    *(bf16x8*)(op + 16) = o2;
  }
}

// ---------------------------------------------------------------------------
// Kernel 3: V transpose — Vt[b][n][t] = v[b][t][n] (bf16), via LDS tiles.
// (round-5 version, reads v at qkv[row][128..192))
// ---------------------------------------------------------------------------
__global__ __launch_bounds__(256) void vtrans(const short* __restrict__ qkv,
                                              short* __restrict__ vt) {
  __shared__ short tile[64][66];
  const int b = blockIdx.y;
  const int tb = blockIdx.x * 64;
  const int tid = threadIdx.x;

  {
    const int tt = tid >> 2, c = (tid & 3) * 16;
    const short* src = qkv + (size_t)(b * T_ + tb + tt) * 192 + 128 + c;
    bf16x8 v0 = *(const bf16x8*)(src);
    bf16x8 v1 = *(const bf16x8*)(src + 8);
    #pragma unroll
    for (int j = 0; j < 8; ++j) { tile[tt][c + j] = v0[j]; tile[tt][c + 8 + j] = v1[j]; }
  }
  __syncthreads();
  {
    const int n = tid >> 2, toff = (tid & 3) * 16;
    short* dst = vt + ((size_t)(b * H_ + n)) * T_ + tb + toff;
    bf16x8 o0, o1;
    #pragma unroll
    for (int j = 0; j < 8; ++j) { o0[j] = tile[toff + j][n]; o1[j] = tile[toff + 8 + j][n]; }
    *(bf16x8*)(dst) = o0;
    *(bf16x8*)(dst + 8) = o1;
  }
}

// ---------------------------------------------------------------------------
// Kernel 4: flash attention, 4-way KV-split, swapped QK^T.
// NEW: XCD-aware 1-D grid (xcd = b&7 -> per-XCD K/V working set 768KB,
// L2-resident) + unconditional batched K/V loads hoisted to tile top.
// ---------------------------------------------------------------------------
#define SCALE_LOG2E 0.18033688011114382f  // 0.125 * log2(e)

__global__ __launch_bounds__(256) void flash(
    const short* __restrict__ qkv, const short* __restrict__ vt,
    float* __restrict__ out) {
  __shared__ __align__(16) short p_lds[4][16][72];
  __shared__ float o_sh[4][16][64];
  __shared__ float ml_sh[4][2][16];

  // XCD swizzle: wgid = ((63-qt) + 64*(b>>3))*8 + (b&7)
  const int wgid = blockIdx.x;
  const int kk = wgid >> 3;
  const int qt = 63 - (kk & 63);            // big tiles dispatched first
  const int b  = (wgid & 7) + 8 * (kk >> 6);

  const int w = threadIdx.x >> 6;
  const int l = threadIdx.x & 63;
  const int lo = l & 15, hi = l >> 4;

  const int dtile = qt >> 2;
  const int ntot = dtile + 1;
  const int span = (ntot + 3) >> 2;
  const int kv0 = w * span;
  const int kv1 = min(ntot, kv0 + span);
  const int qr = qt & 3;

  const short* qrow = qkv + (size_t)(b * T_ + qt * 16 + lo) * 192;  // q at +0
  bf16x8 qf0 = *(const bf16x8*)(qrow + hi * 8);
  bf16x8 qf1 = *(const bf16x8*)(qrow + 32 + hi * 8);

  float m_l = -1e30f;   // running max for q-row `lo` (log2 units)
  float l_l = 0.f;      // running denom for q-row `lo`
  f32x4 oacc[4];
  #pragma unroll
  for (int dt = 0; dt < 4; ++dt) oacc[dt] = (f32x4){0.f, 0.f, 0.f, 0.f};

  for (int kvt = kv0; kvt < kv1; ++kvt) {
    const bool diag = (kvt == dtile);
    const int nct = diag ? (qr + 1) : 4;

    // ---- batch-issue ALL K and V loads for this tile (unconditional,
    // always in-bounds; masked sub-tiles just skip their MFMAs)
    bf16x8 kf[8], vf[8];
    #pragma unroll
    for (int ct = 0; ct < 4; ++ct) {
      const short* krow = qkv + (size_t)(b * T_ + kvt * 64 + ct * 16 + lo) * 192 + 64;
      kf[2 * ct]     = *(const bf16x8*)(krow + hi * 8);
      kf[2 * ct + 1] = *(const bf16x8*)(krow + 32 + hi * 8);
    }
    #pragma unroll
    for (int dt = 0; dt < 4; ++dt) {
      const short* vrow = vt + (size_t)(b * H_ + dt * 16 + lo) * T_ + kvt * 64;
      vf[2 * dt]     = *(const bf16x8*)(vrow + hi * 8);
      vf[2 * dt + 1] = *(const bf16x8*)(vrow + 32 + hi * 8);
    }

    // S^T tile: sv[ct][r] = S[key = ct*16 + hi*4 + r][q-row = lo]
    f32x4 sv[4];
    #pragma unroll
    for (int ct = 0; ct < 4; ++ct) sv[ct] = (f32x4){0.f, 0.f, 0.f, 0.f};
    __builtin_amdgcn_s_setprio(1);
    #pragma unroll
    for (int ct = 0; ct < 4; ++ct) {
      if (ct < nct) {
        sv[ct] = __builtin_amdgcn_mfma_f32_16x16x32_bf16(kf[2 * ct], qf0, sv[ct], 0, 0, 0);
        sv[ct] = __builtin_amdgcn_mfma_f32_16x16x32_bf16(kf[2 * ct + 1], qf1, sv[ct], 0, 0, 0);
      }
    }
    __builtin_amdgcn_s_setprio(0);

    // scale (log2 units) + causal mask
    #pragma unroll
    for (int ct = 0; ct < 4; ++ct) {
      #pragma unroll
      for (int r = 0; r < 4; ++r) {
        float s = (ct < nct) ? sv[ct][r] * SCALE_LOG2E : -1e30f;
        if (diag && ct == qr && (hi * 4 + r) > lo) s = -1e30f;
        sv[ct][r] = s;
      }
    }

    // online softmax for row `lo` (16 keys local; partners via xor 16/32)
    float tmax = sv[0][0];
    #pragma unroll
    for (int ct = 0; ct < 4; ++ct)
      #pragma unroll
      for (int r = 0; r < 4; ++r) tmax = fmaxf(tmax, sv[ct][r]);
    tmax = fmaxf(tmax, __shfl_xor(tmax, 16));
    tmax = fmaxf(tmax, __shfl_xor(tmax, 32));
    const float mn = fmaxf(m_l, tmax);
    const float corr = exp2f(m_l - mn);
    m_l = mn;
    float psum = 0.f;
    #pragma unroll
    for (int ct = 0; ct < 4; ++ct) {
      #pragma unroll
      for (int r = 0; r < 4; ++r) {
        float p = exp2f(sv[ct][r] - mn);
        sv[ct][r] = p;
        psum += p;
      }
    }
    psum += __shfl_xor(psum, 16);
    psum += __shfl_xor(psum, 32);
    l_l = l_l * corr + psum;

    // P -> bf16 (cvt_pk pairs), packed 8B write
    #pragma unroll
    for (int ct = 0; ct < 4; ++ct) {
      __hip_bfloat162 p01 = __float22bfloat162_rn(float2{sv[ct][0], sv[ct][1]});
      __hip_bfloat162 p23 = __float22bfloat162_rn(float2{sv[ct][2], sv[ct][3]});
      uint2 pk;
      pk.x = *reinterpret_cast<unsigned*>(&p01);
      pk.y = *reinterpret_cast<unsigned*>(&p23);
      *reinterpret_cast<uint2*>(&p_lds[w][lo][ct * 16 + hi * 4]) = pk;
    }

    // rescale oacc (rows hi*4+r): fetch corr of that row from lane lo==row
    #pragma unroll
    for (int r = 0; r < 4; ++r) {
      const float cr = __shfl(corr, hi * 4 + r);
      #pragma unroll
      for (int dt = 0; dt < 4; ++dt) oacc[dt][r] *= cr;
    }

    // O += P V
    bf16x8 pa0 = *(const bf16x8*)(&p_lds[w][lo][hi * 8]);
    bf16x8 pa1 = *(const bf16x8*)(&p_lds[w][lo][32 + hi * 8]);
    __builtin_amdgcn_s_setprio(1);
    #pragma unroll
    for (int dt = 0; dt < 4; ++dt) {
      oacc[dt] = __builtin_amdgcn_mfma_f32_16x16x32_bf16(pa0, vf[2 * dt], oacc[dt], 0, 0, 0);
      oacc[dt] = __builtin_amdgcn_mfma_f32_16x16x32_bf16(pa1, vf[2 * dt + 1], oacc[dt], 0, 0, 0);
    }
    __builtin_amdgcn_s_setprio(0);
  }

  // publish partials
  #pragma unroll
  for (int dt = 0; dt < 4; ++dt)
    #pragma unroll
    for (int r = 0; r < 4; ++r)
      o_sh[w][hi * 4 + r][dt * 16 + lo] = oacc[dt][r];
  if (hi == 0) {
    ml_sh[w][0][lo] = m_l;
    ml_sh[w][1][lo] = l_l;
  }
  __syncthreads();

  // merge (log2 units)
  {
    const int row = threadIdx.x >> 4;
    const int c0 = (threadIdx.x & 15) * 4;
    float M = fmaxf(fmaxf(ml_sh[0][0][row], ml_sh[1][0][row]),
                    fmaxf(ml_sh[2][0][row], ml_sh[3][0][row]));
    float e[4];
    float L = 0.f;
    #pragma unroll
    for (int w2 = 0; w2 < 4; ++w2) {
      e[w2] = exp2f(ml_sh[w2][0][row] - M);
      L += ml_sh[w2][1][row] * e[w2];
    }
    f32x4 o;
    #pragma unroll
    for (int j = 0; j < 4; ++j) {
      float O = 0.f;
      #pragma unroll
      for (int w2 = 0; w2 < 4; ++w2) O += e[w2] * o_sh[w2][row][c0 + j];
      o[j] = O / L;
    }
    *(f32x4*)(out + (size_t)(b * T_ + qt * 16 + row) * H_ + c0) = o;
  }
}

// ---------------------------------------------------------------------------
extern "C" void kernel_launch(void* const* d_in, const int* in_sizes, int n_in,
                              void* d_out, int out_size, void* d_ws, size_t ws_size,
                              hipStream_t stream) {
  const float* x  = (const float*)d_in[0];
  const float* Wq = (const float*)d_in[1];
  const float* bq = (const float*)d_in[2];
  const float* Wk = (const float*)d_in[3];
  const float* bk = (const float*)d_in[4];
  const float* Wv = (const float*)d_in[5];
  const float* bv = (const float*)d_in[6];
  float* out = (float*)d_out;

  // workspace layout (shorts): wfrag | qkv(interleaved, stride 192) | vt
  short* wfrag = (short*)d_ws;
  short* qkv = wfrag + (size_t)3 * H_ * C_;          // 147456
  short* vtb = qkv + (size_t)B_ * T_ * 192;          // +3145728

  prep_w<<<dim3(576), dim3(256), 0, stream>>>(Wq, Wk, Wv, wfrag);
  qkv_gemm<<<dim3(1024), dim3(128), 0, stream>>>(x, wfrag, bq, bk, bv, qkv);
  vtrans<<<dim3(T_ / 64, B_), dim3(256), 0, stream>>>(qkv, vtb);
  flash<<<dim3(1024), dim3(256), 0, stream>>>(qkv, vtb, out);
}